// Round 1
// baseline (8737.907 us; speedup 1.0000x reference)
//
#include <hip/hip_runtime.h>

namespace {

constexpr int B = 64;
constexpr int L = 2048;
constexpr int Q = 256;
constexpr int S = 26;
constexpr float EPS = 1e-16f;
constexpr size_t POST = (size_t)B * L * Q;  // offset of loglik output

__device__ __forceinline__ float wave_max64(float x) {
#pragma unroll
  for (int off = 32; off > 0; off >>= 1)
    x = fmaxf(x, __shfl_xor(x, off, 64));
  return x;
}

__device__ __forceinline__ float wave_sum64(float x) {
#pragma unroll
  for (int off = 32; off > 0; off >>= 1)
    x += __shfl_xor(x, off, 64);
  return x;
}

// Forward: one WG per batch b. 256 threads = 4 waves.
//   wave w = tid>>6, lane = tid&63. Owner state q = 64w + lane.
//   Thread holds A columns: Areg[c][jj] = expA[64w+jj][64c+lane]  (j-chunk = wave's).
//   Writes alpha into out[b,t,q] (post layout) and loglik at out[POST+b].
__global__ __launch_bounds__(256, 1)
void hmm_forward(const float* __restrict__ inputs, const float* __restrict__ log_A,
                 const float* __restrict__ log_pi, const float* __restrict__ log_B,
                 float* __restrict__ out) {
  const int b    = blockIdx.x;
  const int tid  = threadIdx.x;
  const int w    = tid >> 6;
  const int lane = tid & 63;
  const int q    = (w << 6) | lane;

  __shared__ alignas(16) float vbuf[2][Q];   // double-buffered exp(alpha - m)
  __shared__ float part[16][64];             // [jchunk*4 + stateblock][lane]
  __shared__ alignas(16) float red[4];       // per-wave maxes
  __shared__ alignas(16) float red2[4];      // loglik partials

  // --- one-time register loads ---
  float Areg[4][64];
#pragma unroll
  for (int c = 0; c < 4; ++c) {
#pragma unroll
    for (int jj = 0; jj < 64; ++jj) {
      Areg[c][jj] = __expf(log_A[(w * 64 + jj) * Q + c * 64 + lane]);  // coalesced
    }
  }
  float eB[S];
#pragma unroll
  for (int s = 0; s < S; ++s) eB[s] = __expf(log_B[q * S + s]);

  const float* __restrict__ inp_b  = inputs + (size_t)b * L * S;
  float* __restrict__       post_b = out + (size_t)b * L * Q;

  // --- t = 0: alpha0 = log_pi + e0 ---
  float e;
  {
    const float* ip = inp_b;
    float accm = EPS;
#pragma unroll
    for (int s = 0; s < S; ++s) accm = fmaf(ip[s], eB[s], accm);
    e = __logf(accm);
  }
  float a = log_pi[q] + e;
  post_b[q] = a;
  float wm = wave_max64(a);
  if (lane == 0) red[w] = wm;
  __syncthreads();
  float4 r4 = *(const float4*)red;
  float m = fmaxf(fmaxf(r4.x, r4.y), fmaxf(r4.z, r4.w));
  vbuf[0][q] = __expf(a - m);
  __syncthreads();

  int p = 0;
  for (int t = 1; t < L; ++t) {
    // emission for this t (wave-uniform loads; overlaps the FMA loop)
    const float* ip = inp_b + t * S;
    float accm = EPS;
#pragma unroll
    for (int s = 0; s < S; ++s) accm = fmaf(ip[s], eB[s], accm);
    e = __logf(accm);

    // matvec partials over this wave's j-chunk (v broadcast from LDS)
    const float4* vb = (const float4*)(&vbuf[p][w * 64]);
    float acc[4] = {0.f, 0.f, 0.f, 0.f};
#pragma unroll
    for (int j4 = 0; j4 < 16; ++j4) {
      const float4 vv = vb[j4];
#pragma unroll
      for (int c = 0; c < 4; ++c) {
        acc[c] = fmaf(vv.x, Areg[c][4 * j4 + 0], acc[c]);
        acc[c] = fmaf(vv.y, Areg[c][4 * j4 + 1], acc[c]);
        acc[c] = fmaf(vv.z, Areg[c][4 * j4 + 2], acc[c]);
        acc[c] = fmaf(vv.w, Areg[c][4 * j4 + 3], acc[c]);
      }
    }
#pragma unroll
    for (int c = 0; c < 4; ++c) part[w * 4 + c][lane] = acc[c];
    __syncthreads();  // B1: partials visible

    float tot = part[0 * 4 + w][lane] + part[1 * 4 + w][lane] +
                part[2 * 4 + w][lane] + part[3 * 4 + w][lane];
    a = __logf(tot) + m + e;
    post_b[(size_t)t * Q + q] = a;
    wm = wave_max64(a);
    if (lane == 0) red[w] = wm;
    __syncthreads();  // B2: red visible (part reads also done)

    r4 = *(const float4*)red;
    m = fmaxf(fmaxf(r4.x, r4.y), fmaxf(r4.z, r4.w));
    vbuf[p ^ 1][q] = __expf(a - m);
    __syncthreads();  // B3: new v visible
    p ^= 1;
  }

  // loglik = logsumexp(alpha_{L-1})
  float vfin = __expf(a - m);
  float s4 = wave_sum64(vfin);
  if (lane == 0) red2[w] = s4;
  __syncthreads();
  if (tid == 0) {
    out[POST + b] = __logf(red2[0] + red2[1] + red2[2] + red2[3]) + m;
  }
}

// Backward: one WG per batch. Thread holds A rows: Areg[c][jj] = expA[64c+lane][64w+jj].
// Finalizes post[b,t,q] = alpha + beta - loglik in place.
__global__ __launch_bounds__(256, 1)
void hmm_backward(const float* __restrict__ inputs, const float* __restrict__ log_A,
                  const float* __restrict__ log_B, float* __restrict__ out) {
  const int b    = blockIdx.x;
  const int tid  = threadIdx.x;
  const int w    = tid >> 6;
  const int lane = tid & 63;
  const int q    = (w << 6) | lane;

  __shared__ alignas(16) float wbuf[Q];
  __shared__ float part[16][64];
  __shared__ alignas(16) float red[4];

  float Areg[4][64];
#pragma unroll
  for (int c = 0; c < 4; ++c) {
#pragma unroll
    for (int jj = 0; jj < 64; ++jj) {
      Areg[c][jj] = __expf(log_A[(c * 64 + lane) * Q + w * 64 + jj]);
    }
  }
  float eB[S];
#pragma unroll
  for (int s = 0; s < S; ++s) eB[s] = __expf(log_B[q * S + s]);

  const float* __restrict__ inp_b  = inputs + (size_t)b * L * S;
  float* __restrict__       post_b = out + (size_t)b * L * Q;
  const float ll = out[POST + b];

  // t = L-1: beta = 0 -> post = alpha - ll
  post_b[(size_t)(L - 1) * Q + q] += -ll;
  float beta = 0.f;

  for (int t = L - 2; t >= 0; --t) {
    // prefetch alpha for this t early (hides global latency across the body)
    float aprev = post_b[(size_t)t * Q + q];

    // u_j = e_{t+1}[j] + beta_{t+1}[j]
    const float* ip = inp_b + (t + 1) * S;
    float accm = EPS;
#pragma unroll
    for (int s = 0; s < S; ++s) accm = fmaf(ip[s], eB[s], accm);
    float u = __logf(accm) + beta;
    float wm = wave_max64(u);
    if (lane == 0) red[w] = wm;
    __syncthreads();  // B1

    float4 r4 = *(const float4*)red;
    float m = fmaxf(fmaxf(r4.x, r4.y), fmaxf(r4.z, r4.w));
    wbuf[q] = __expf(u - m);
    __syncthreads();  // B2

    const float4* vb = (const float4*)(&wbuf[w * 64]);
    float acc[4] = {0.f, 0.f, 0.f, 0.f};
#pragma unroll
    for (int j4 = 0; j4 < 16; ++j4) {
      const float4 vv = vb[j4];
#pragma unroll
      for (int c = 0; c < 4; ++c) {
        acc[c] = fmaf(vv.x, Areg[c][4 * j4 + 0], acc[c]);
        acc[c] = fmaf(vv.y, Areg[c][4 * j4 + 1], acc[c]);
        acc[c] = fmaf(vv.z, Areg[c][4 * j4 + 2], acc[c]);
        acc[c] = fmaf(vv.w, Areg[c][4 * j4 + 3], acc[c]);
      }
    }
#pragma unroll
    for (int c = 0; c < 4; ++c) part[w * 4 + c][lane] = acc[c];
    __syncthreads();  // B3

    float tot = part[0 * 4 + w][lane] + part[1 * 4 + w][lane] +
                part[2 * 4 + w][lane] + part[3 * 4 + w][lane];
    beta = __logf(tot) + m;
    post_b[(size_t)t * Q + q] = aprev + beta - ll;
  }
}

}  // namespace

extern "C" void kernel_launch(void* const* d_in, const int* in_sizes, int n_in,
                              void* d_out, int out_size, void* d_ws, size_t ws_size,
                              hipStream_t stream) {
  const float* inputs = (const float*)d_in[0];
  const float* log_A  = (const float*)d_in[1];
  const float* log_pi = (const float*)d_in[2];
  const float* log_B  = (const float*)d_in[3];
  float* out = (float*)d_out;

  hipLaunchKernelGGL(hmm_forward, dim3(B), dim3(256), 0, stream,
                     inputs, log_A, log_pi, log_B, out);
  hipLaunchKernelGGL(hmm_backward, dim3(B), dim3(256), 0, stream,
                     inputs, log_A, log_B, out);
}

// Round 2
// 2853.568 us; speedup vs baseline: 3.0621x; 3.0621x over previous
//
#include <hip/hip_runtime.h>

namespace {

constexpr int B = 64;
constexpr int L = 2048;
constexpr int Q = 256;
constexpr int S = 26;
constexpr float EPS = 1e-16f;
constexpr size_t POST = (size_t)B * L * Q;  // loglik offset in d_out

typedef float v2f __attribute__((ext_vector_type(2)));

__device__ __forceinline__ float wave_max64(float x) {
#pragma unroll
  for (int off = 32; off > 0; off >>= 1) x = fmaxf(x, __shfl_xor(x, off, 64));
  return x;
}
__device__ __forceinline__ float wave_sum64(float x) {
#pragma unroll
  for (int off = 32; off > 0; off >>= 1) x += __shfl_xor(x, off, 64);
  return x;
}

// ---------------- forward ----------------
// 512 threads = 8 waves. Wave w owns j-chunk [32w, 32w+32).
// Thread (w,lane) accumulates partials for i in {lane, 64+lane, 128+lane, 192+lane}.
// Reducer waves 0-3: thread owns state r = 64w + lane (final reduce, a, v, output).
__device__ __forceinline__ void fwd_impl(int b, const float* __restrict__ inputs,
                                         const float* __restrict__ log_A,
                                         const float* __restrict__ log_pi,
                                         const float* __restrict__ log_B,
                                         float* __restrict__ out) {
  const int tid = threadIdx.x, w = tid >> 6, lane = tid & 63;
  const int j0 = w * 32;
  const int r = ((w & 3) << 6) | lane;
  const bool red_w = (w < 4);

  __shared__ alignas(16) float vbuf[Q];
  __shared__ float part[8][Q];
  __shared__ float redb[2][4];

  // Ar[c][k] = (expA[j0+2k][64c+lane], expA[j0+2k+1][64c+lane])  -- 128 floats
  v2f Ar[4][16];
#pragma unroll
  for (int c = 0; c < 4; ++c)
#pragma unroll
    for (int k = 0; k < 16; ++k) {
      Ar[c][k].x = __expf(log_A[(size_t)(j0 + 2 * k) * Q + c * 64 + lane]);
      Ar[c][k].y = __expf(log_A[(size_t)(j0 + 2 * k + 1) * Q + c * 64 + lane]);
    }
  float eB[S];
  if (red_w) {
#pragma unroll
    for (int s = 0; s < S; ++s) eB[s] = __expf(log_B[r * S + s]);
  }
  const float* __restrict__ inp_b = inputs + (size_t)b * L * S;
  float* __restrict__ post_b = out + (size_t)b * L * Q;

  float a = 0.f, Ssh = 0.f;
  // t = 0
  if (red_w) {
    const float* ip = inp_b;
    float accm = EPS;
#pragma unroll
    for (int s = 0; s < S; ++s) accm = fmaf(ip[s], eB[s], accm);
    a = __logf(accm) + log_pi[r];
    post_b[r] = a;
    float wm = wave_max64(a);
    if (lane == 0) redb[0][w] = wm;
  }
  __syncthreads();
  if (red_w) {
    Ssh = fmaxf(fmaxf(redb[0][0], redb[0][1]), fmaxf(redb[0][2], redb[0][3]));
    vbuf[r] = __expf(a - Ssh);  // v built with shift Ssh
  }
  __syncthreads();

  int p = 0;  // redb[p] holds wave-maxes of a_{t-1}
  for (int t = 1; t < L; ++t) {
    float e = 0.f;
    if (red_w) {  // emission for t (wave-uniform scalar loads, overlap matvec)
      const float* ip = inp_b + t * S;
      float accm = EPS;
#pragma unroll
      for (int s = 0; s < S; ++s) accm = fmaf(ip[s], eB[s], accm);
      e = __logf(accm);
    }
    // matvec partials over this wave's j-chunk (v broadcast from LDS)
    const v2f* vb = (const v2f*)&vbuf[j0];
    v2f a0 = {0.f, 0.f}, a1 = {0.f, 0.f}, a2 = {0.f, 0.f}, a3 = {0.f, 0.f};
#pragma unroll
    for (int k = 0; k < 16; ++k) {
      v2f vv = vb[k];
      a0 = __builtin_elementwise_fma(vv, Ar[0][k], a0);
      a1 = __builtin_elementwise_fma(vv, Ar[1][k], a1);
      a2 = __builtin_elementwise_fma(vv, Ar[2][k], a2);
      a3 = __builtin_elementwise_fma(vv, Ar[3][k], a3);
    }
    part[w][lane]       = a0.x + a0.y;
    part[w][64 + lane]  = a1.x + a1.y;
    part[w][128 + lane] = a2.x + a2.y;
    part[w][192 + lane] = a3.x + a3.y;
    __syncthreads();  // B1: partials visible; vbuf reads complete
    if (red_w) {
      float tot = 0.f;
#pragma unroll
      for (int ww = 0; ww < 8; ++ww) tot += part[ww][r];
      a = __logf(tot) + Ssh + e;  // Ssh = shift used building current v
      post_b[(size_t)t * Q + r] = a;
      // one-step-stale global max as next shift (safe: |drift| << 80)
      float Snew = fmaxf(fmaxf(redb[p][0], redb[p][1]), fmaxf(redb[p][2], redb[p][3]));
      vbuf[r] = __expf(a - Snew);
      float wm = wave_max64(a);
      if (lane == 0) redb[p ^ 1][w] = wm;
      Ssh = Snew;
    }
    __syncthreads();  // B2: vbuf + redb visible
    p ^= 1;
  }

  // loglik = logsumexp(a_{L-1}); redb[p] now holds wave-maxes of a_{L-1}
  if (red_w) {
    float Sf = fmaxf(fmaxf(redb[p][0], redb[p][1]), fmaxf(redb[p][2], redb[p][3]));
    float sm = wave_sum64(__expf(a - Sf));
    if (lane == 0) {
      part[0][w] = sm;
      part[1][w] = Sf;
    }
  }
  __syncthreads();
  if (tid == 0) {
    out[POST + b] = __logf(part[0][0] + part[0][1] + part[0][2] + part[0][3]) + part[1][0];
  }
}

// ---------------- backward ----------------
// MODE 0: write beta to ws (concurrent with forward). MODE 1: fused RMW post += beta - ll.
template <int MODE>
__device__ __forceinline__ void bwd_impl(int b, const float* __restrict__ inputs,
                                         const float* __restrict__ log_A,
                                         const float* __restrict__ log_B,
                                         float* __restrict__ out,
                                         float* __restrict__ ws) {
  const int tid = threadIdx.x, w = tid >> 6, lane = tid & 63;
  const int j0 = w * 32;
  const int r = ((w & 3) << 6) | lane;
  const bool red_w = (w < 4);

  __shared__ alignas(16) float wbuf[Q];
  __shared__ float part[8][Q];
  __shared__ float redb[2][4];

  // Ar[c][k] = (expA[64c+lane][j0+2k], expA[64c+lane][j0+2k+1])  (A^T matvec)
  v2f Ar[4][16];
#pragma unroll
  for (int c = 0; c < 4; ++c)
#pragma unroll
    for (int k = 0; k < 16; ++k) {
      const float* row = log_A + (size_t)(c * 64 + lane) * Q + j0;
      Ar[c][k].x = __expf(row[2 * k]);
      Ar[c][k].y = __expf(row[2 * k + 1]);
    }
  float eB[S];
  if (red_w) {
#pragma unroll
    for (int s = 0; s < S; ++s) eB[s] = __expf(log_B[r * S + s]);
  }
  const float* __restrict__ inp_b = inputs + (size_t)b * L * S;
  float* __restrict__ post_b = out + (size_t)b * L * Q;
  float* __restrict__ ws_b = ws + (size_t)b * L * Q;

  float ll = 0.f;
  if (MODE == 1) ll = out[POST + b];

  // t = L-1: beta = 0
  if (red_w) {
    if (MODE == 0) ws_b[(size_t)(L - 1) * Q + r] = 0.f;
    else           post_b[(size_t)(L - 1) * Q + r] += -ll;
  }

  float beta = 0.f, u = 0.f, Ssh = 0.f, aprev = 0.f;
  // init: u^{(L-2)} = e_{L-1} + 0
  if (red_w) {
    const float* ip = inp_b + (size_t)(L - 1) * S;
    float accm = EPS;
#pragma unroll
    for (int s = 0; s < S; ++s) accm = fmaf(ip[s], eB[s], accm);
    u = __logf(accm);
    float wm = wave_max64(u);
    if (lane == 0) redb[0][w] = wm;
    if (MODE == 1) aprev = post_b[(size_t)(L - 2) * Q + r];
  }
  __syncthreads();
  if (red_w) {
    Ssh = fmaxf(fmaxf(redb[0][0], redb[0][1]), fmaxf(redb[0][2], redb[0][3]));
    wbuf[r] = __expf(u - Ssh);
  }
  __syncthreads();

  int p = 0;  // redb[p] holds wave-maxes of current u
  for (int t = L - 2; t >= 0; --t) {
    // matvec: acc_i = sum_j A[i][j] * wbuf[j] over this wave's j-chunk
    const v2f* vb = (const v2f*)&wbuf[j0];
    v2f a0 = {0.f, 0.f}, a1 = {0.f, 0.f}, a2 = {0.f, 0.f}, a3 = {0.f, 0.f};
#pragma unroll
    for (int k = 0; k < 16; ++k) {
      v2f vv = vb[k];
      a0 = __builtin_elementwise_fma(vv, Ar[0][k], a0);
      a1 = __builtin_elementwise_fma(vv, Ar[1][k], a1);
      a2 = __builtin_elementwise_fma(vv, Ar[2][k], a2);
      a3 = __builtin_elementwise_fma(vv, Ar[3][k], a3);
    }
    part[w][lane]       = a0.x + a0.y;
    part[w][64 + lane]  = a1.x + a1.y;
    part[w][128 + lane] = a2.x + a2.y;
    part[w][192 + lane] = a3.x + a3.y;
    __syncthreads();  // B1: partials visible; wbuf reads complete
    if (red_w) {
      float tot = 0.f;
#pragma unroll
      for (int ww = 0; ww < 8; ++ww) tot += part[ww][r];
      beta = __logf(tot) + Ssh;
      if (MODE == 0) ws_b[(size_t)t * Q + r] = beta;
      else           post_b[(size_t)t * Q + r] = aprev + beta - ll;
      if (t > 0) {
        // u^{(t-1)} = e_t + beta_t ; next shift = stale max of u^{(t)}
        const float* ip = inp_b + (size_t)t * S;
        float accm = EPS;
#pragma unroll
        for (int s = 0; s < S; ++s) accm = fmaf(ip[s], eB[s], accm);
        u = __logf(accm) + beta;
        float Snew = fmaxf(fmaxf(redb[p][0], redb[p][1]), fmaxf(redb[p][2], redb[p][3]));
        wbuf[r] = __expf(u - Snew);
        float wm = wave_max64(u);
        if (lane == 0) redb[p ^ 1][w] = wm;
        Ssh = Snew;
        if (MODE == 1) aprev = post_b[(size_t)(t - 1) * Q + r];
      }
    }
    __syncthreads();  // B2: wbuf + redb visible
    p ^= 1;
  }
}

// ---------------- kernels ----------------
__global__ __launch_bounds__(512, 2) void hmm_fwdbwd(const float* __restrict__ inputs,
                                                     const float* __restrict__ log_A,
                                                     const float* __restrict__ log_pi,
                                                     const float* __restrict__ log_B,
                                                     float* __restrict__ out,
                                                     float* __restrict__ ws) {
  if (blockIdx.x < B) fwd_impl(blockIdx.x, inputs, log_A, log_pi, log_B, out);
  else                bwd_impl<0>(blockIdx.x - B, inputs, log_A, log_B, out, ws);
}

__global__ __launch_bounds__(256) void hmm_combine(const float* __restrict__ ws,
                                                   float* __restrict__ out) {
  const size_t idx = (size_t)blockIdx.x * 256 + threadIdx.x;  // float4 index
  const int b = (int)(idx >> 17);  // L*Q/4 = 131072 float4 per batch
  const float ll = out[POST + b];
  float4 a = ((const float4*)out)[idx];
  const float4 be = ((const float4*)ws)[idx];
  a.x += be.x - ll;
  a.y += be.y - ll;
  a.z += be.z - ll;
  a.w += be.w - ll;
  ((float4*)out)[idx] = a;
}

__global__ __launch_bounds__(512, 2) void hmm_fwd_only(const float* __restrict__ inputs,
                                                       const float* __restrict__ log_A,
                                                       const float* __restrict__ log_pi,
                                                       const float* __restrict__ log_B,
                                                       float* __restrict__ out) {
  fwd_impl(blockIdx.x, inputs, log_A, log_pi, log_B, out);
}

__global__ __launch_bounds__(512, 2) void hmm_bwd_fused(const float* __restrict__ inputs,
                                                        const float* __restrict__ log_A,
                                                        const float* __restrict__ log_B,
                                                        float* __restrict__ out) {
  bwd_impl<1>(blockIdx.x, inputs, log_A, log_B, out, nullptr);
}

}  // namespace

extern "C" void kernel_launch(void* const* d_in, const int* in_sizes, int n_in,
                              void* d_out, int out_size, void* d_ws, size_t ws_size,
                              hipStream_t stream) {
  const float* inputs = (const float*)d_in[0];
  const float* log_A  = (const float*)d_in[1];
  const float* log_pi = (const float*)d_in[2];
  const float* log_B  = (const float*)d_in[3];
  float* out = (float*)d_out;
  float* ws  = (float*)d_ws;

  if (ws_size >= POST * sizeof(float)) {
    // forward and backward run concurrently (independent); combine afterwards
    hipLaunchKernelGGL(hmm_fwdbwd, dim3(2 * B), dim3(512), 0, stream,
                       inputs, log_A, log_pi, log_B, out, ws);
    hipLaunchKernelGGL(hmm_combine, dim3((unsigned)(POST / 4 / 256)), dim3(256), 0, stream,
                       ws, out);
  } else {
    hipLaunchKernelGGL(hmm_fwd_only, dim3(B), dim3(512), 0, stream,
                       inputs, log_A, log_pi, log_B, out);
    hipLaunchKernelGGL(hmm_bwd_fused, dim3(B), dim3(512), 0, stream,
                       inputs, log_A, log_B, out);
  }
}

// Round 3
// 2282.243 us; speedup vs baseline: 3.8286x; 1.2503x over previous
//
#include <hip/hip_runtime.h>

namespace {

constexpr int B = 64;
constexpr int L = 2048;
constexpr int Q = 256;
constexpr int S = 26;
constexpr float EPS = 1e-16f;
constexpr size_t POST = (size_t)B * L * Q;  // loglik offset in d_out

typedef float v2f __attribute__((ext_vector_type(2)));

// One barrier per step. Wave w owns j-chunk AND state-chunk [32w, 32w+32).
// part[] is the only cross-wave handoff -> double buffered.
struct Smem {
  float part[2][8][Q];        // 16 KB partials
  alignas(16) float vb[8][32];// per-wave v = exp(x - shift), wave-local
  float sh[2];                // broadcast shift (state-0 value), dbuf
  alignas(16) float afin[Q];  // final alpha (loglik reduce, one-time)
};

__device__ __forceinline__ float wave_max64(float x) {
#pragma unroll
  for (int off = 32; off > 0; off >>= 1) x = fmaxf(x, __shfl_xor(x, off, 64));
  return x;
}
__device__ __forceinline__ float wave_sum64(float x) {
#pragma unroll
  for (int off = 32; off > 0; off >>= 1) x += __shfl_xor(x, off, 64);
  return x;
}

__device__ __forceinline__ float emit_log(const float* __restrict__ ip,
                                          const float* __restrict__ eB) {
  float acc = EPS;
#pragma unroll
  for (int s = 0; s < S; ++s) acc = fmaf(ip[s], eB[s], acc);
  return __logf(acc);
}

// acc_i = sum over this wave's j-chunk of v_j * Ar[.][j], for the lane's 4 i's
__device__ __forceinline__ void matvec32(const v2f Ar[4][16],
                                         const float* __restrict__ vbw,
                                         float o[4]) {
  const float4* vb4 = (const float4*)vbw;
  v2f a0 = {0.f, 0.f}, a1 = {0.f, 0.f}, a2 = {0.f, 0.f}, a3 = {0.f, 0.f};
#pragma unroll
  for (int k4 = 0; k4 < 8; ++k4) {
    float4 vv = vb4[k4];
    v2f p0 = {vv.x, vv.y}, p1 = {vv.z, vv.w};
    a0 = __builtin_elementwise_fma(p0, Ar[0][2 * k4], a0);
    a1 = __builtin_elementwise_fma(p0, Ar[1][2 * k4], a1);
    a2 = __builtin_elementwise_fma(p0, Ar[2][2 * k4], a2);
    a3 = __builtin_elementwise_fma(p0, Ar[3][2 * k4], a3);
    a0 = __builtin_elementwise_fma(p1, Ar[0][2 * k4 + 1], a0);
    a1 = __builtin_elementwise_fma(p1, Ar[1][2 * k4 + 1], a1);
    a2 = __builtin_elementwise_fma(p1, Ar[2][2 * k4 + 1], a2);
    a3 = __builtin_elementwise_fma(p1, Ar[3][2 * k4 + 1], a3);
  }
  o[0] = a0.x + a0.y;
  o[1] = a1.x + a1.y;
  o[2] = a2.x + a2.y;
  o[3] = a3.x + a3.y;
}

// ---------------- forward ----------------
__device__ __forceinline__ void fwd_impl(int b, const float* __restrict__ inputs,
                                         const float* __restrict__ log_A,
                                         const float* __restrict__ log_pi,
                                         const float* __restrict__ log_B,
                                         float* __restrict__ out, Smem& sm) {
  const int tid = threadIdx.x, w = tid >> 6, lane = tid & 63;
  const int l31 = lane & 31;
  const bool lo = lane < 32;
  const int r = w * 32 + l31;  // owned state
  const int j0 = w * 32;       // owned j-chunk

  // Ar[c][k] = {expA[j0+2k][64c+lane], expA[j0+2k+1][64c+lane]}
  v2f Ar[4][16];
#pragma unroll
  for (int c = 0; c < 4; ++c)
#pragma unroll
    for (int k = 0; k < 16; ++k) {
      Ar[c][k].x = __expf(log_A[(size_t)(j0 + 2 * k) * Q + c * 64 + lane]);
      Ar[c][k].y = __expf(log_A[(size_t)(j0 + 2 * k + 1) * Q + c * 64 + lane]);
    }
  float eB[S];
#pragma unroll
  for (int s = 0; s < S; ++s) eB[s] = __expf(log_B[r * S + s]);

  const float* __restrict__ inp_b = inputs + (size_t)b * L * S;
  float* __restrict__ post_b = out + (size_t)b * L * Q;

  // t = 0
  float alpha = emit_log(inp_b, eB) + log_pi[r];
  if (lo) post_b[r] = alpha;
  if (tid == 0) sm.sh[0] = alpha;
  __syncthreads();
  float Ssh = sm.sh[0];  // shift used to build current v
  if (lo) sm.vb[w][l31] = __expf(alpha - Ssh);

  int bi = 0;
  for (int t = 1; t < L; ++t) {
    // phase A: emission + matvec + partial stores (no barrier since tail:
    // vb is wave-local, part[bi] flips buffers)
    float e = emit_log(inp_b + (size_t)t * S, eB);
    float o[4];
    matvec32(Ar, sm.vb[w], o);
    sm.part[bi][w][lane] = o[0];
    sm.part[bi][w][64 + lane] = o[1];
    sm.part[bi][w][128 + lane] = o[2];
    sm.part[bi][w][192 + lane] = o[3];
    __syncthreads();  // the only barrier per step

    // tail: finish own 32 states (both half-waves duplicate compute)
    float shc = sm.sh[bi];
    float tot = 0.f;
#pragma unroll
    for (int w2 = 0; w2 < 8; ++w2) tot += sm.part[bi][w2][r];
    alpha = __logf(tot) + Ssh + e;
    if (lo) post_b[(size_t)t * Q + r] = alpha;
    if (tid == 0) sm.sh[bi ^ 1] = alpha;  // next step's shift (state 0)
    if (lo) sm.vb[w][l31] = __expf(alpha - shc);
    Ssh = shc;
    bi ^= 1;
  }

  // loglik = exact logsumexp(alpha_{L-1})
  if (lo) sm.afin[r] = alpha;
  __syncthreads();
  if (w == 0) {
    float4 fa = ((const float4*)sm.afin)[lane];
    float m = fmaxf(fmaxf(fa.x, fa.y), fmaxf(fa.z, fa.w));
    m = wave_max64(m);
    float ss = __expf(fa.x - m) + __expf(fa.y - m) + __expf(fa.z - m) + __expf(fa.w - m);
    ss = wave_sum64(ss);
    if (lane == 0) out[POST + b] = __logf(ss) + m;
  }
}

// ---------------- backward ----------------
// MODE 0: write beta to ws (runs concurrently with forward).
// MODE 1: fused sequential fallback: post = alpha + beta - ll.
template <int MODE>
__device__ __forceinline__ void bwd_impl(int b, const float* __restrict__ inputs,
                                         const float* __restrict__ log_A,
                                         const float* __restrict__ log_B,
                                         float* __restrict__ out,
                                         float* __restrict__ ws, Smem& sm) {
  const int tid = threadIdx.x, w = tid >> 6, lane = tid & 63;
  const int l31 = lane & 31;
  const bool lo = lane < 32;
  const int r = w * 32 + l31;
  const int j0 = w * 32;

  // Ar[c][k] = {expA[64c+lane][j0+2k], expA[64c+lane][j0+2k+1]}  (A, not A^T)
  v2f Ar[4][16];
#pragma unroll
  for (int c = 0; c < 4; ++c)
#pragma unroll
    for (int k = 0; k < 16; ++k) {
      const float* row = log_A + (size_t)(c * 64 + lane) * Q + j0;
      Ar[c][k].x = __expf(row[2 * k]);
      Ar[c][k].y = __expf(row[2 * k + 1]);
    }
  float eB[S];
#pragma unroll
  for (int s = 0; s < S; ++s) eB[s] = __expf(log_B[r * S + s]);

  const float* __restrict__ inp_b = inputs + (size_t)b * L * S;
  float* __restrict__ post_b = out + (size_t)b * L * Q;
  float* __restrict__ ws_b = ws + (size_t)b * L * Q;

  float ll = 0.f;
  if (MODE == 1) ll = out[POST + b];

  // u for beta_{L-2}: u_r = e_{L-1}(r) + beta_{L-1}(=0)
  float u = emit_log(inp_b + (size_t)(L - 1) * S, eB);
  if (lo) {
    if (MODE == 0) ws_b[(size_t)(L - 1) * Q + r] = 0.f;
    else post_b[(size_t)(L - 1) * Q + r] += -ll;
  }
  if (tid == 0) sm.sh[0] = u;
  __syncthreads();
  float Ssh = sm.sh[0];
  if (lo) sm.vb[w][l31] = __expf(u - Ssh);

  int bi = 0;
  for (int t = L - 2; t >= 0; --t) {
    float e = emit_log(inp_b + (size_t)t * S, eB);
    float aprev = 0.f;
    if (MODE == 1) aprev = post_b[(size_t)t * Q + r];  // prefetch alpha
    float o[4];
    matvec32(Ar, sm.vb[w], o);
    sm.part[bi][w][lane] = o[0];
    sm.part[bi][w][64 + lane] = o[1];
    sm.part[bi][w][128 + lane] = o[2];
    sm.part[bi][w][192 + lane] = o[3];
    __syncthreads();

    float shc = sm.sh[bi];
    float tot = 0.f;
#pragma unroll
    for (int w2 = 0; w2 < 8; ++w2) tot += sm.part[bi][w2][r];
    float beta = __logf(tot) + Ssh;
    if (lo) {
      if (MODE == 0) ws_b[(size_t)t * Q + r] = beta;
      else post_b[(size_t)t * Q + r] = aprev + beta - ll;
    }
    if (t > 0) {
      u = e + beta;
      if (tid == 0) sm.sh[bi ^ 1] = u;
      if (lo) sm.vb[w][l31] = __expf(u - shc);
      Ssh = shc;
    }
    bi ^= 1;
  }
}

// ---------------- kernels ----------------
__global__ __launch_bounds__(512, 2)
void hmm_fwdbwd(const float* __restrict__ inputs, const float* __restrict__ log_A,
                const float* __restrict__ log_pi, const float* __restrict__ log_B,
                float* __restrict__ out, float* __restrict__ ws) {
  __shared__ Smem sm;
  if (blockIdx.x < B) fwd_impl(blockIdx.x, inputs, log_A, log_pi, log_B, out, sm);
  else                bwd_impl<0>(blockIdx.x - B, inputs, log_A, log_B, out, ws, sm);
}

__global__ __launch_bounds__(256)
void hmm_combine(const float* __restrict__ ws, float* __restrict__ out) {
  const size_t idx = (size_t)blockIdx.x * 256 + threadIdx.x;  // float4 index
  const int b = (int)(idx >> 17);  // L*Q/4 = 131072 float4 per batch
  const float ll = out[POST + b];
  float4 a = ((const float4*)out)[idx];
  const float4 be = ((const float4*)ws)[idx];
  a.x += be.x - ll;
  a.y += be.y - ll;
  a.z += be.z - ll;
  a.w += be.w - ll;
  ((float4*)out)[idx] = a;
}

__global__ __launch_bounds__(512, 2)
void hmm_fwd_only(const float* __restrict__ inputs, const float* __restrict__ log_A,
                  const float* __restrict__ log_pi, const float* __restrict__ log_B,
                  float* __restrict__ out) {
  __shared__ Smem sm;
  fwd_impl(blockIdx.x, inputs, log_A, log_pi, log_B, out, sm);
}

__global__ __launch_bounds__(512, 2)
void hmm_bwd_fused(const float* __restrict__ inputs, const float* __restrict__ log_A,
                   const float* __restrict__ log_B, float* __restrict__ out) {
  __shared__ Smem sm;
  bwd_impl<1>(blockIdx.x, inputs, log_A, log_B, out, nullptr, sm);
}

}  // namespace

extern "C" void kernel_launch(void* const* d_in, const int* in_sizes, int n_in,
                              void* d_out, int out_size, void* d_ws, size_t ws_size,
                              hipStream_t stream) {
  const float* inputs = (const float*)d_in[0];
  const float* log_A  = (const float*)d_in[1];
  const float* log_pi = (const float*)d_in[2];
  const float* log_B  = (const float*)d_in[3];
  float* out = (float*)d_out;
  float* ws  = (float*)d_ws;

  if (ws_size >= POST * sizeof(float)) {
    hipLaunchKernelGGL(hmm_fwdbwd, dim3(2 * B), dim3(512), 0, stream,
                       inputs, log_A, log_pi, log_B, out, ws);
    hipLaunchKernelGGL(hmm_combine, dim3((unsigned)(POST / 4 / 256)), dim3(256), 0, stream,
                       ws, out);
  } else {
    hipLaunchKernelGGL(hmm_fwd_only, dim3(B), dim3(512), 0, stream,
                       inputs, log_A, log_pi, log_B, out);
    hipLaunchKernelGGL(hmm_bwd_fused, dim3(B), dim3(512), 0, stream,
                       inputs, log_A, log_B, out);
  }
}